// Round 3
// baseline (89302.179 us; speedup 1.0000x reference)
//
#include <hip/hip_runtime.h>

// 2-layer LSTM (H=256, T=256, B=512, I=2) + linear head.
// Persistent-weight scheme: 256 blocks = 32 unit-groups x 8 batch-groups.
// Block owns 8 units (32 gate-rows x 768 k weights, RESIDENT in LDS) and
// 64 batches. Per step only h moves: 3 x 16KB h-streams from L2 (chunked,
// double-buffered through LDS), h-slices exchanged via workspace with
// bgroup-scoped counter barriers (device-scope atomics + agent fences).
// lane = (unit, batch): 4 gate accs, cell update fully local, no reductions.
// LDS 133 KB forces 1 block/CU -> all 256 blocks co-resident (spin-safe).

typedef float vf2 __attribute__((ext_vector_type(2)));
typedef float vf4 __attribute__((ext_vector_type(4)));

#define TSTEPS 256
#define NT 512
#define UGN 32          // blocks per batch-group (arrival target)

// ws float offsets
#define WG_OFF   0                        // [32 ug][32 row][768 k]
#define WX_OFF   (WG_OFF + 32*32*768)     // [2 xi][1024 = 4u+g]
#define B1_OFF   (WX_OFF + 2*1024)        // [1024]
#define B2_OFF   (B1_OFF + 1024)          // [1024]
#define HBUF     (256*512)                // one h buffer: [256 u][512 b]
#define H1_OFF   (B2_OFF + 1024)          // [2][HBUF]
#define H2_OFF   (H1_OFF + 2*HBUF)        // [2][HBUF]
#define CTR_OFF  (H2_OFF + 2*HBUF)        // [8 bg][512 slots] ints

__global__ void prep_kernel(const float* __restrict__ W_ih1,
                            const float* __restrict__ W_hh1,
                            const float* __restrict__ b_ih1,
                            const float* __restrict__ b_hh1,
                            const float* __restrict__ W_ih2,
                            const float* __restrict__ W_hh2,
                            const float* __restrict__ b_ih2,
                            const float* __restrict__ b_hh2,
                            float* __restrict__ ws) {
    const int stride = gridDim.x * blockDim.x;
    const int idx = blockIdx.x * blockDim.x + threadIdx.x;
    // weight slab: ws[ug][row][k], row = local_unit*4 + gate,
    // k: [0,256) = W_hh1, [256,512) = W_ih2, [512,768) = W_hh2
    for (int i = idx; i < 32*32*768; i += stride) {
        int ug = i / (32*768), r = (i / 768) % 32, k = i % 768;
        int gr = ((r & 3) << 8) + ug * 8 + (r >> 2);   // gate*256 + unit
        float v;
        if (k < 256)      v = W_hh1[gr * 256 + k];
        else if (k < 512) v = W_ih2[gr * 256 + (k - 256)];
        else              v = W_hh2[gr * 256 + (k - 512)];
        ws[WG_OFF + i] = v;
    }
    for (int i = idx; i < 2*1024; i += stride) {
        int xi = i >> 10, c = i & 1023;
        ws[WX_OFF + i] = W_ih1[(((c & 3) << 8) + (c >> 2)) * 2 + xi];
    }
    for (int i = idx; i < 1024; i += stride) {
        int gr = ((i & 3) << 8) + (i >> 2);
        ws[B1_OFF + i] = b_ih1[gr] + b_hh1[gr];
        ws[B2_OFF + i] = b_ih2[gr] + b_hh2[gr];
    }
    // zero the parity-1 h buffers (initial state) and the barrier counters
    for (int i = idx; i < HBUF; i += stride) {
        ws[H1_OFF + HBUF + i] = 0.f;
        ws[H2_OFF + HBUF + i] = 0.f;
    }
    int* ctr = (int*)(ws + CTR_OFF);
    for (int i = idx; i < 8*512; i += stride) ctr[i] = 0;
}

__device__ __forceinline__ float sig_(float v) {
    return 1.f / (1.f + __expf(-v));
}
__device__ __forceinline__ float tanh_(float v) {
    return 1.f - 2.f / (__expf(2.f * v) + 1.f);
}

__global__ __launch_bounds__(NT) void lstm_kernel(
    const float* __restrict__ x,      // (512, 256, 2)
    float* __restrict__ ws,
    const float* __restrict__ W_lin,  // (2, 256)
    const float* __restrict__ b_lin,  // (2,)
    float* __restrict__ out)          // (512, 256, 2)
{
    __shared__ float wsm[32 * 768];    // resident weights: [row][k]   98304 B
    __shared__ float chk[2][64][64];   // h chunk double-buffer         32768 B
    __shared__ float wlin[2][256];     // linear head                    2048 B

    const int tid = threadIdx.x, lane = tid & 63, wv = tid >> 6;
    const int rowg = wv >> 1, bhalf = wv & 1;
    const int u_loc = lane >> 5, bl = lane & 31, bloc = bhalf * 32 + bl;
    const int ug = blockIdx.x >> 3, bg = blockIdx.x & 7;  // &7: XCD-affinity heuristic
    const int uloc8 = rowg * 2 + u_loc;       // local unit 0..7
    const int ur4 = uloc8 * 4;                // weight row base
    const int u = ug * 8 + uloc8;             // global unit
    const int b = bg * 64 + bloc;             // global batch
    const bool ywave = (rowg == 0);

    // stage resident weights + W_lin into LDS (first section barrier covers)
    {
        const vf4* src = (const vf4*)(ws + WG_OFF + ug * (32 * 768));
        vf4* dst = (vf4*)wsm;
        for (int i = tid; i < 32 * 768 / 4; i += NT) dst[i] = src[i];
        if (tid < 128) ((vf4*)wlin)[tid] = ((const vf4*)W_lin)[tid];
    }
    const vf4 b1v  = *(const vf4*)(ws + B1_OFF + 4 * u);
    const vf4 b2v  = *(const vf4*)(ws + B2_OFF + 4 * u);
    const vf4 wx0v = *(const vf4*)(ws + WX_OFF + 4 * u);
    const vf4 wx1v = *(const vf4*)(ws + WX_OFF + 1024 + 4 * u);
    const float blv = b_lin[u_loc];
    int* ctr = (int*)(ws + CTR_OFF) + bg * 512;
    float* H1[2] = { ws + H1_OFF, ws + H1_OFF + HBUF };
    float* H2[2] = { ws + H2_OFF, ws + H2_OFF + HBUF };

    float c1 = 0.f, c2 = 0.f;
    float acc0, acc1, acc2, acc3, yac = 0.f;
    vf4 s0, s1;                                // staging registers
    const int srow = 8 * wv + (lane >> 4);     // chunk row this lane stages
    const int scol = (lane & 15) * 4;

    // stream 4x16KB chunks of one h-vector (64 batches x 256 units) from
    // global, double-buffered via LDS; FMA against resident weights.
    auto section = [&](const float* hsrc, int kwb, bool doY) {
        const float* p0 = hsrc + srow * 512 + bg * 64 + scol;
        s0 = *(const vf4*)p0; s1 = *(const vf4*)(p0 + 4 * 512);
        { float* d = &chk[0][srow][scol]; *(vf4*)d = s0; *(vf4*)(d + 4 * 64) = s1; }
        s0 = *(const vf4*)(p0 + 64 * 512); s1 = *(const vf4*)(p0 + 64 * 512 + 4 * 512);
        __syncthreads();
        #pragma unroll
        for (int ci = 0; ci < 4; ++ci) {
            const int kb = kwb + ci * 64, cb = ci * 64;
            #pragma unroll
            for (int q = 0; q < 16; ++q) {
                const int kin = 4 * q;
                const float h0 = chk[ci & 1][kin + 0][bloc];
                const float h1 = chk[ci & 1][kin + 1][bloc];
                const float h2 = chk[ci & 1][kin + 2][bloc];
                const float h3 = chk[ci & 1][kin + 3][bloc];
                const vf4 w0 = *(const vf4*)&wsm[(ur4 + 0) * 768 + kb + kin];
                const vf4 w1 = *(const vf4*)&wsm[(ur4 + 1) * 768 + kb + kin];
                const vf4 w2 = *(const vf4*)&wsm[(ur4 + 2) * 768 + kb + kin];
                const vf4 w3 = *(const vf4*)&wsm[(ur4 + 3) * 768 + kb + kin];
                acc0 += w0.x * h0 + w0.y * h1 + w0.z * h2 + w0.w * h3;
                acc1 += w1.x * h0 + w1.y * h1 + w1.z * h2 + w1.w * h3;
                acc2 += w2.x * h0 + w2.y * h1 + w2.z * h2 + w2.w * h3;
                acc3 += w3.x * h0 + w3.y * h1 + w3.z * h2 + w3.w * h3;
                if (doY) {
                    const vf4 wl = *(const vf4*)&wlin[u_loc][cb + kin];
                    yac += wl.x * h0 + wl.y * h1 + wl.z * h2 + wl.w * h3;
                }
            }
            if (ci < 3) {
                float* d = &chk[(ci + 1) & 1][srow][scol];
                *(vf4*)d = s0; *(vf4*)(d + 4 * 64) = s1;
                if (ci < 2) {
                    const float* pn = p0 + (ci + 2) * 64 * 512;
                    s0 = *(const vf4*)pn; s1 = *(const vf4*)(pn + 4 * 512);
                }
                __syncthreads();
            }
        }
    };

    auto arrive = [&](int slot) {
        __syncthreads();   // drains this block's global h stores
        if (tid == 0) {
            __builtin_amdgcn_fence(__ATOMIC_RELEASE, "agent");
            __hip_atomic_fetch_add(&ctr[slot], 1, __ATOMIC_RELEASE,
                                   __HIP_MEMORY_SCOPE_AGENT);
        }
    };
    auto wait = [&](int slot) {
        if (tid == 0) {
            while (__hip_atomic_load(&ctr[slot], __ATOMIC_ACQUIRE,
                                     __HIP_MEMORY_SCOPE_AGENT) < UGN)
                __builtin_amdgcn_s_sleep(1);
        }
        __syncthreads();
        __builtin_amdgcn_fence(__ATOMIC_ACQUIRE, "agent");
    };

    vf2 xa = *(const vf2*)(x + (size_t)b * (TSTEPS * 2));

    #pragma unroll 1
    for (int t = 0; t < TSTEPS; ++t) {
        // ---- phase 1: gates1 = b1 + Wx*x_t + Whh1*h1(t-1) ----
        acc0 = b1v.x + wx0v.x * xa.x + wx1v.x * xa.y;
        acc1 = b1v.y + wx0v.y * xa.x + wx1v.y * xa.y;
        acc2 = b1v.z + wx0v.z * xa.x + wx1v.z * xa.y;
        acc3 = b1v.w + wx0v.w * xa.x + wx1v.w * xa.y;
        section(H1[(t + 1) & 1], 0, false);
        {
            float iv = sig_(acc0), fv = sig_(acc1), gv = tanh_(acc2), ov = sig_(acc3);
            c1 = fv * c1 + iv * gv;
            H1[t & 1][u * 512 + b] = ov * tanh_(c1);
        }
        arrive(2 * t);                       // sync1 post (h1(t) published)

        // ---- phase 2a: hh2 * h2(t-1)  (+ deferred y(t-1)) ----
        if (t > 0) wait(2 * t - 1);          // sync2(t-1); hidden by phase 1
        acc0 = b2v.x; acc1 = b2v.y; acc2 = b2v.z; acc3 = b2v.w;
        yac = 0.f;
        section(H2[(t + 1) & 1], 512, ywave);
        if (t > 0 && ug == 0 && ywave)
            out[(size_t)b * (TSTEPS * 2) + (t - 1) * 2 + u_loc] = yac + blv;
        xa = *(const vf2*)(x + (size_t)b * (TSTEPS * 2) + ((t + 1) & (TSTEPS - 1)) * 2);

        // ---- phase 2b: ih2 * h1(t) ----
        wait(2 * t);                         // sync1; hidden by 2a compute
        section(H1[t & 1], 256, false);
        {
            float iv = sig_(acc0), fv = sig_(acc1), gv = tanh_(acc2), ov = sig_(acc3);
            c2 = fv * c2 + iv * gv;
            H2[t & 1][u * 512 + b] = ov * tanh_(c2);
        }
        arrive(2 * t + 1);                   // sync2 post (h2(t) published)
    }

    // ---- tail: y(255) from h2(255) ----
    if (ug == 0) {
        wait(511);
        acc0 = acc1 = acc2 = acc3 = 0.f; yac = 0.f;
        section(H2[1], 512, ywave);          // h2(255) lives in parity-1 buffer
        if (ywave)
            out[(size_t)b * (TSTEPS * 2) + 255 * 2 + u_loc] = yac + blv;
    }
}

extern "C" void kernel_launch(void* const* d_in, const int* in_sizes, int n_in,
                              void* d_out, int out_size, void* d_ws, size_t ws_size,
                              hipStream_t stream) {
    const float* x     = (const float*)d_in[0];
    const float* W_ih1 = (const float*)d_in[1];
    const float* W_hh1 = (const float*)d_in[2];
    const float* b_ih1 = (const float*)d_in[3];
    const float* b_hh1 = (const float*)d_in[4];
    const float* W_ih2 = (const float*)d_in[5];
    const float* W_hh2 = (const float*)d_in[6];
    const float* b_ih2 = (const float*)d_in[7];
    const float* b_hh2 = (const float*)d_in[8];
    const float* W_lin = (const float*)d_in[9];
    const float* b_lin = (const float*)d_in[10];
    float* ws  = (float*)d_ws;
    float* out = (float*)d_out;

    prep_kernel<<<256, 256, 0, stream>>>(W_ih1, W_hh1, b_ih1, b_hh1,
                                         W_ih2, W_hh2, b_ih2, b_hh2, ws);
    lstm_kernel<<<256, NT, 0, stream>>>(x, ws, W_lin, b_lin, out);
}

// Round 4
// 4274.457 us; speedup vs baseline: 20.8921x; 20.8921x over previous
//
#include <hip/hip_runtime.h>

// 2-layer LSTM (H=256, T=256, B=512, I=2) + linear head.
// 128 blocks x 1024 threads, 4 batch elements per block, t-loop in-kernel.
// Weight stream in fp16 (1.5 MB/step/CU, L2-resident, NO duplication:
// thread tid owns gate-row j=tid for all 4 batches). Gates via
// v_dot2_f32_f16 (fp16 x fp16 -> fp32 acc). h in LDS as fp16 (wave-
// broadcast b128 reads), c in registers, 4 barriers/step, 4-deep register
// pipeline on the weight stream wrapping across layers and timesteps.
// Round-3 lesson: NO cross-block exchange (agent fences forced L2 flushes
// -> 213 GB HBM). Everything batch-local.

typedef float vf2 __attribute__((ext_vector_type(2)));
typedef _Float16 vh2 __attribute__((ext_vector_type(2)));
typedef _Float16 vh4 __attribute__((ext_vector_type(4)));
typedef _Float16 vh8 __attribute__((ext_vector_type(8)));

#define NT 1024
#define TSTEPS 256
#define NCH 96            // chunks per step; chunk = 8 k-values, all 1024 rows
#define CHB 16384         // bytes per chunk = 1024 threads * 16 B
// fp32 table offsets (in floats) after the 1.5 MB fp16 stream
#define FS 393216         // = NCH*CHB/4
// layout: wf[FS+j]=W_ih1[j][0], wf[FS+1024+j]=W_ih1[j][1],
//         wf[FS+2048+j]=b_ih1[j]+b_hh1[j], wf[FS+3072+j]=b_ih2[j]+b_hh2[j]

__global__ void prep_kernel(const float* __restrict__ W_ih1,
                            const float* __restrict__ W_hh1,
                            const float* __restrict__ b_ih1,
                            const float* __restrict__ b_hh1,
                            const float* __restrict__ W_ih2,
                            const float* __restrict__ W_hh2,
                            const float* __restrict__ b_ih2,
                            const float* __restrict__ b_hh2,
                            void* __restrict__ ws) {
    const int stride = gridDim.x * blockDim.x;
    const int idx = blockIdx.x * blockDim.x + threadIdx.x;
    _Float16* wh = (_Float16*)ws;
    float* wf = (float*)ws;
    // stream element e: chunk ch = e>>13, t = (e&8191)>>3, i = e&7
    // row j = t, k = 8*ch + i;  k<256: W_hh1 | k<512: W_ih2 | else W_hh2
    for (int e = idx; e < NCH * 8192; e += stride) {
        int ch = e >> 13, rem = e & 8191, t = rem >> 3, i = rem & 7;
        int j = t, k = (ch << 3) + i;
        float v;
        if (k < 256)      v = W_hh1[j * 256 + k];
        else if (k < 512) v = W_ih2[j * 256 + (k - 256)];
        else              v = W_hh2[j * 256 + (k - 512)];
        wh[e] = (_Float16)v;
    }
    for (int j = idx; j < 1024; j += stride) {
        wf[FS + j]        = W_ih1[j * 2 + 0];
        wf[FS + 1024 + j] = W_ih1[j * 2 + 1];
        wf[FS + 2048 + j] = b_ih1[j] + b_hh1[j];
        wf[FS + 3072 + j] = b_ih2[j] + b_hh2[j];
    }
}

__device__ __forceinline__ float sig_(float v) {
    return 1.f / (1.f + __expf(-v));
}
__device__ __forceinline__ float tanh_(float v) {
    return 1.f - 2.f / (__expf(2.f * v) + 1.f);
}
__device__ __forceinline__ float fdot2_(vh2 a, vh2 b, float c) {
#if __has_builtin(__builtin_amdgcn_fdot2)
    return __builtin_amdgcn_fdot2(a, b, c, false);
#else
    return c + (float)a.x * (float)b.x + (float)a.y * (float)b.y;
#endif
}

__global__ __launch_bounds__(NT) void lstm_kernel(
    const float* __restrict__ x,      // (512, 256, 2)
    const void* __restrict__ ws,
    const float* __restrict__ W_lin,  // (2, 256)
    const float* __restrict__ b_lin,  // (2,)
    float* __restrict__ out)          // (512, 256, 2)
{
    __shared__ float gbuf[4][1024];        // gate preacts [batch][gate-row]
    __shared__ _Float16 hl1[2][4][256];    // h1 [parity][batch][unit]
    __shared__ _Float16 hl2[2][4][256];    // h2

    const int tid = threadIdx.x;
    const int j = tid;                     // owned gate-row (j = gate*256+unit)
    const int u = tid & 255, bu = tid >> 8;  // cell-update task: unit u, batch bu
    const int b0 = blockIdx.x * 4;
    const char* wstream = (const char*)ws;
    const float* wf = (const float*)ws;

    const float wx0 = wf[FS + j], wx1 = wf[FS + 1024 + j];
    const float bj1 = wf[FS + 2048 + j], bj2 = wf[FS + 3072 + j];

    // y-head: waves 0..7 -> (batch ob, output oo); lane covers 4 units
    const int lane = tid & 63, wv = tid >> 6;
    const int ob = (wv >> 1) & 3, oo = wv & 1;
    const float wl0 = W_lin[oo * 256 + 4 * lane + 0];
    const float wl1 = W_lin[oo * 256 + 4 * lane + 1];
    const float wl2 = W_lin[oo * 256 + 4 * lane + 2];
    const float wl3 = W_lin[oo * 256 + 4 * lane + 3];
    const float blin = b_lin[oo];

    for (int i = tid; i < 2 * 4 * 256; i += NT) {
        ((_Float16*)hl1)[i] = (_Float16)0.f;
        ((_Float16*)hl2)[i] = (_Float16)0.f;
    }

    float c1 = 0.f, c2 = 0.f;
    vf2 xv0 = *(const vf2*)(x + (size_t)(b0 + 0) * 512);
    vf2 xv1 = *(const vf2*)(x + (size_t)(b0 + 1) * 512);
    vf2 xv2 = *(const vf2*)(x + (size_t)(b0 + 2) * 512);
    vf2 xv3 = *(const vf2*)(x + (size_t)(b0 + 3) * 512);

    const int t16 = tid * 16;
    int sp = 0;                            // uniform stream byte offset
    float acc[4];

    auto loadc = [&](vh8& dst) {
        dst = *(const vh8*)(wstream + sp + t16);
        sp += CHB;
        if (sp == NCH * CHB) sp = 0;
    };
    auto usec = [&](vh8 w, const _Float16 (*hp)[256], int k0) {
        vh2 w0; w0.x = w[0]; w0.y = w[1];
        vh2 w1; w1.x = w[2]; w1.y = w[3];
        vh2 w2; w2.x = w[4]; w2.y = w[5];
        vh2 w3; w3.x = w[6]; w3.y = w[7];
        #pragma unroll
        for (int b = 0; b < 4; ++b) {
            vh8 hv = *(const vh8*)&hp[b][k0];
            vh2 h0; h0.x = hv[0]; h0.y = hv[1];
            vh2 h1; h1.x = hv[2]; h1.y = hv[3];
            vh2 h2; h2.x = hv[4]; h2.y = hv[5];
            vh2 h3; h3.x = hv[6]; h3.y = hv[7];
            float a = acc[b];
            a = fdot2_(w0, h0, a);
            a = fdot2_(w1, h1, a);
            a = fdot2_(w2, h2, a);
            a = fdot2_(w3, h3, a);
            acc[b] = a;
        }
    };

    vh8 bA, bB, bC, bD;
    loadc(bA); loadc(bB); loadc(bC); loadc(bD);
    __syncthreads();

    auto gemm32 = [&](const _Float16 (*hp)[256]) {
        #pragma unroll 1
        for (int q = 0; q < 32; q += 4) {
            usec(bA, hp, 8 * q);      loadc(bA);
            usec(bB, hp, 8 * q + 8);  loadc(bB);
            usec(bC, hp, 8 * q + 16); loadc(bC);
            usec(bD, hp, 8 * q + 24); loadc(bD);
        }
    };

    #pragma unroll 1
    for (int t = 0; t < TSTEPS; ++t) {
        const int p = t & 1, pm = p ^ 1;

        // ---- layer 1 gates: b1 + Wih1*x_t + Whh1*h1(t-1) ----
        acc[0] = bj1 + wx0 * xv0.x + wx1 * xv0.y;
        acc[1] = bj1 + wx0 * xv1.x + wx1 * xv1.y;
        acc[2] = bj1 + wx0 * xv2.x + wx1 * xv2.y;
        acc[3] = bj1 + wx0 * xv3.x + wx1 * xv3.y;
        gemm32(hl1[pm]);
        gbuf[0][j] = acc[0]; gbuf[1][j] = acc[1];
        gbuf[2][j] = acc[2]; gbuf[3][j] = acc[3];
        __syncthreads();

        // ---- layer 1 cell update (thread -> unit u, batch bu) ----
        {
            float gi = sig_(gbuf[bu][u]);
            float gf = sig_(gbuf[bu][256 + u]);
            float gg = tanh_(gbuf[bu][512 + u]);
            float go = sig_(gbuf[bu][768 + u]);
            c1 = gf * c1 + gi * gg;
            hl1[p][bu][u] = (_Float16)(go * tanh_(c1));
        }
        __syncthreads();

        // ---- layer 2 gates: b2 + Wih2*h1(t) + Whh2*h2(t-1) ----
        acc[0] = bj2; acc[1] = bj2; acc[2] = bj2; acc[3] = bj2;
        gemm32(hl1[p]);
        gemm32(hl2[pm]);
        gbuf[0][j] = acc[0]; gbuf[1][j] = acc[1];
        gbuf[2][j] = acc[2]; gbuf[3][j] = acc[3];
        __syncthreads();

        // ---- layer 2 cell update ----
        {
            float gi = sig_(gbuf[bu][u]);
            float gf = sig_(gbuf[bu][256 + u]);
            float gg = tanh_(gbuf[bu][512 + u]);
            float go = sig_(gbuf[bu][768 + u]);
            c2 = gf * c2 + gi * gg;
            hl2[p][bu][u] = (_Float16)(go * tanh_(c2));
        }
        __syncthreads();

        // ---- y = h2 @ W_lin.T + b_lin (waves 0..7) ----
        if (wv < 8) {
            vh4 hv = *(const vh4*)&hl2[p][ob][4 * lane];
            float s = (float)hv.x * wl0 + (float)hv.y * wl1
                    + (float)hv.z * wl2 + (float)hv.w * wl3;
            #pragma unroll
            for (int m = 32; m >= 1; m >>= 1) s += __shfl_xor(s, m, 64);
            if (lane == 0)
                out[(size_t)(b0 + ob) * 512 + t * 2 + oo] = s + blin;
        }

        // prefetch x for t+1 (wraps harmlessly at the end)
        const int tn = (t + 1) & (TSTEPS - 1);
        xv0 = *(const vf2*)(x + (size_t)(b0 + 0) * 512 + tn * 2);
        xv1 = *(const vf2*)(x + (size_t)(b0 + 1) * 512 + tn * 2);
        xv2 = *(const vf2*)(x + (size_t)(b0 + 2) * 512 + tn * 2);
        xv3 = *(const vf2*)(x + (size_t)(b0 + 3) * 512 + tn * 2);
    }
}

extern "C" void kernel_launch(void* const* d_in, const int* in_sizes, int n_in,
                              void* d_out, int out_size, void* d_ws, size_t ws_size,
                              hipStream_t stream) {
    const float* x     = (const float*)d_in[0];
    const float* W_ih1 = (const float*)d_in[1];
    const float* W_hh1 = (const float*)d_in[2];
    const float* b_ih1 = (const float*)d_in[3];
    const float* b_hh1 = (const float*)d_in[4];
    const float* W_ih2 = (const float*)d_in[5];
    const float* W_hh2 = (const float*)d_in[6];
    const float* b_ih2 = (const float*)d_in[7];
    const float* b_hh2 = (const float*)d_in[8];
    const float* W_lin = (const float*)d_in[9];
    const float* b_lin = (const float*)d_in[10];
    float* out = (float*)d_out;

    prep_kernel<<<256, 256, 0, stream>>>(W_ih1, W_hh1, b_ih1, b_hh1,
                                         W_ih2, W_hh2, b_ih2, b_hh2, d_ws);
    lstm_kernel<<<128, NT, 0, stream>>>(x, d_ws, W_lin, b_lin, out);
}